// Round 1
// baseline (102.372 us; speedup 1.0000x reference)
//
#include <hip/hip_runtime.h>
#include <math.h>

#define NB 32
#define NS 4096
#define ND 160
#define NM 16
#define NR 16
#define TOK 64
#define NCHUNK (NS / TOK)   // 64 chunks of 64 tokens

// ---------------------------------------------------------------------------
// Kernel 1: read path (q_proj -> scores -> softmax -> c16 -> read_out)
//           + fused partial column-sum of `interface` into ws.
// grid = (NCHUNK, NB), block = 256
// ---------------------------------------------------------------------------
__global__ __launch_bounds__(256) void ulm_read_kernel(
    const float* __restrict__ query,
    const float* __restrict__ iface,
    const float* __restrict__ memory,
    const float* __restrict__ Wrk,     // [NR][ND]
    const float* __restrict__ Wrv,     // [ND][NR]
    float* __restrict__ read_out,      // [NB][NS][ND]
    float* __restrict__ ipart)         // [NB*NCHUNK][ND] partial sums
{
    __shared__ float4 sQ4[TOK * 40];                 // swizzled query tile (40 KB)
    __shared__ __align__(16) float sWrk[NR * ND];    // 10 KB
    __shared__ __align__(16) float sWrvT[NR * ND];   // Wrv transposed [r][d], 10 KB
    __shared__ float sMem16[NM * NR];                // memory[b][m][0:16]
    __shared__ float sP[TOK * 17];                   // q_proj, padded
    __shared__ __align__(16) float sC[TOK * 20];     // c16, padded to 20 (16B align)

    const int t = threadIdx.x;
    const int chunk = blockIdx.x;
    const int b = blockIdx.y;
    const int s0 = chunk * TOK;

    const float4* q4g = reinterpret_cast<const float4*>(query + ((size_t)b * NS + s0) * ND);
    const float4* i4g = reinterpret_cast<const float4*>(iface + ((size_t)b * NS + s0) * ND);

    // --- stage weights -----------------------------------------------------
    for (int i = t; i < NR * ND; i += 256) sWrk[i] = Wrk[i];
    for (int i = t; i < NR * ND; i += 256) {
        int r = i / ND, d = i - r * ND;
        sWrvT[i] = Wrv[d * NR + r];                  // transpose (tiny, L2-cached)
    }
    if (t < NM * NR) {
        int m = t >> 4, r = t & 15;
        sMem16[t] = memory[((size_t)b * NM + m) * ND + r];
    }

    // --- Phase A: query tile -> LDS, XOR-swizzled at float4 granularity ----
    // row stride 40 f4 (160 f32 = 0 mod 32 banks) would put all lanes on one
    // 4-bank group in Phase B; d4 ^= (tok&7) spreads rows over all 8 groups.
#pragma unroll
    for (int k = 0; k < 10; ++k) {
        int i = t + k * 256;                          // 0..2559
        int tok = i / 40, d4 = i - tok * 40;
        sQ4[tok * 40 + (d4 ^ (tok & 7))] = q4g[i];
    }

    // --- Phase I part 1: interface partial sums into registers -------------
    const int d4i = t % 40;
    const int tg = t / 40;                            // 0..5 active, 6 idle (t>=240)
    float4 iacc = make_float4(0.f, 0.f, 0.f, 0.f);
    if (tg < 6) {
        for (int tok = tg; tok < TOK; tok += 6) {
            float4 v = i4g[tok * 40 + d4i];
            iacc.x += v.x; iacc.y += v.y; iacc.z += v.z; iacc.w += v.w;
        }
    }

    __syncthreads();

    // --- Phase B: q_proj[tok][r] = dot(Q[tok], Wrk[r]) ----------------------
    // token = lane (64 distinct rows / wave), rg wave-uniform -> W reads broadcast
    {
        const int tok = t & 63;
        const int rg = t >> 6;                        // 0..3, uniform per wave
        float a0 = 0.f, a1 = 0.f, a2 = 0.f, a3 = 0.f;
        const float4* w0p = reinterpret_cast<const float4*>(&sWrk[(rg * 4 + 0) * ND]);
        const float4* w1p = reinterpret_cast<const float4*>(&sWrk[(rg * 4 + 1) * ND]);
        const float4* w2p = reinterpret_cast<const float4*>(&sWrk[(rg * 4 + 2) * ND]);
        const float4* w3p = reinterpret_cast<const float4*>(&sWrk[(rg * 4 + 3) * ND]);
        const int qbase = tok * 40;
        const int xm = tok & 7;
#pragma unroll 8
        for (int d4 = 0; d4 < 40; ++d4) {
            float4 q = sQ4[qbase + (d4 ^ xm)];
            float4 w;
            w = w0p[d4]; a0 += q.x * w.x + q.y * w.y + q.z * w.z + q.w * w.w;
            w = w1p[d4]; a1 += q.x * w.x + q.y * w.y + q.z * w.z + q.w * w.w;
            w = w2p[d4]; a2 += q.x * w.x + q.y * w.y + q.z * w.z + q.w * w.w;
            w = w3p[d4]; a3 += q.x * w.x + q.y * w.y + q.z * w.z + q.w * w.w;
        }
        sP[tok * 17 + rg * 4 + 0] = a0;
        sP[tok * 17 + rg * 4 + 1] = a1;
        sP[tok * 17 + rg * 4 + 2] = a2;
        sP[tok * 17 + rg * 4 + 3] = a3;
    }
    __syncthreads();

    // --- Phase C: scores -> softmax -> c16 (one thread per token) ----------
    if (t < TOK) {
        float p[NR];
#pragma unroll
        for (int r = 0; r < NR; ++r) p[r] = sP[t * 17 + r];
        float sc[NM];
        float mx = -1e30f;
#pragma unroll
        for (int m = 0; m < NM; ++m) {
            float s = 0.f;
#pragma unroll
            for (int r = 0; r < NR; ++r) s += p[r] * sMem16[m * NR + r];
            s *= 0.25f;                               // 1/sqrt(16)
            sc[m] = s;
            mx = fmaxf(mx, s);
        }
        float sum = 0.f;
#pragma unroll
        for (int m = 0; m < NM; ++m) { float e = __expf(sc[m] - mx); sc[m] = e; sum += e; }
        float inv = 1.f / sum;
        float c[NR];
#pragma unroll
        for (int r = 0; r < NR; ++r) c[r] = 0.f;
#pragma unroll
        for (int m = 0; m < NM; ++m) {
            float a = sc[m] * inv;
#pragma unroll
            for (int r = 0; r < NR; ++r) c[r] += a * sMem16[m * NR + r];
        }
#pragma unroll
        for (int r = 0; r < NR; ++r) sC[t * 20 + r] = c[r];
    }
    __syncthreads();

    // --- Phase I part 2: stash partials in LDS (aliases dead sQ4) ----------
    float4* sRed = sQ4;
    if (tg < 6) sRed[tg * 40 + d4i] = iacc;

    // --- Phase D prep: Wrv column slice into registers ---------------------
    float4 wreg[16];
    if (tg < 6) {
        const float4* wt4 = reinterpret_cast<const float4*>(sWrvT);
#pragma unroll
        for (int r = 0; r < 16; ++r) wreg[r] = wt4[r * 40 + d4i];
    }
    __syncthreads();

    // finish interface partial reduction: 6 copies -> 1, store to ws
    if (t < 40) {
        float4 tot = make_float4(0.f, 0.f, 0.f, 0.f);
#pragma unroll
        for (int g = 0; g < 6; ++g) {
            float4 v = sRed[g * 40 + t];
            tot.x += v.x; tot.y += v.y; tot.z += v.z; tot.w += v.w;
        }
        float4* op = reinterpret_cast<float4*>(ipart + ((size_t)(b * NCHUNK + chunk)) * ND);
        op[t] = tot;
    }

    // --- Phase D: read_out[tok][d] = sum_r c16[tok][r] * WrvT[r][d] ---------
#define AXPY(a, wv) { o.x += (a) * (wv).x; o.y += (a) * (wv).y; o.z += (a) * (wv).z; o.w += (a) * (wv).w; }
    if (tg < 6) {
        for (int tok = tg; tok < TOK; tok += 6) {
            const float4* c4 = reinterpret_cast<const float4*>(&sC[tok * 20]);
            float4 c0 = c4[0], c1 = c4[1], c2 = c4[2], c3 = c4[3];
            float4 o = make_float4(0.f, 0.f, 0.f, 0.f);
            AXPY(c0.x, wreg[0])  AXPY(c0.y, wreg[1])  AXPY(c0.z, wreg[2])  AXPY(c0.w, wreg[3])
            AXPY(c1.x, wreg[4])  AXPY(c1.y, wreg[5])  AXPY(c1.z, wreg[6])  AXPY(c1.w, wreg[7])
            AXPY(c2.x, wreg[8])  AXPY(c2.y, wreg[9])  AXPY(c2.z, wreg[10]) AXPY(c2.w, wreg[11])
            AXPY(c3.x, wreg[12]) AXPY(c3.y, wreg[13]) AXPY(c3.z, wreg[14]) AXPY(c3.w, wreg[15])
            float4* outp = reinterpret_cast<float4*>(read_out + ((size_t)b * NS + s0 + tok) * ND);
            outp[d4i] = o;
        }
    }
#undef AXPY
}

// ---------------------------------------------------------------------------
// Kernel 2: write path. i_mean -> i_proj -> erase/add -> layer_norm(new_mem)
// grid = NB, block = 256
// ---------------------------------------------------------------------------
__global__ __launch_bounds__(256) void ulm_write_kernel(
    const float* __restrict__ memory,
    const float* __restrict__ Wwk,     // [NR][ND]
    const float* __restrict__ Wwe,     // [ND][NR]
    const float* __restrict__ Wwa,     // [ND][NR]
    const float* __restrict__ ipart,   // [NB*NCHUNK][ND]
    float* __restrict__ new_mem)       // [NB][NM][ND]
{
    __shared__ float sIm[ND];
    __shared__ float sIp[NR];
    __shared__ float sOmE[ND];   // 1 - erase
    __shared__ float sAdd[ND];

    const int b = blockIdx.x;
    const int t = threadIdx.x;

    if (t < ND) {
        float acc = 0.f;
        for (int c = 0; c < NCHUNK; ++c)
            acc += ipart[((size_t)(b * NCHUNK + c)) * ND + t];
        sIm[t] = acc * (1.0f / NS);
    }
    __syncthreads();

    if (t < NR) {
        float acc = 0.f;
        for (int d = 0; d < ND; ++d) acc += sIm[d] * Wwk[t * ND + d];
        sIp[t] = acc;
    }
    __syncthreads();

    if (t < ND) {
        float e = 0.f, a = 0.f;
#pragma unroll
        for (int r = 0; r < NR; ++r) {
            float ip = sIp[r];
            e += ip * Wwe[t * NR + r];
            a += ip * Wwa[t * NR + r];
        }
        sOmE[t] = 1.0f - 1.0f / (1.0f + __expf(-e));
        sAdd[t] = a;
    }
    __syncthreads();

    // layer norm each of the 16 memory rows; one wave per row
    const int wave = t >> 6, lane = t & 63;
    for (int m = wave; m < NM; m += 4) {
        const float* mrow = memory + ((size_t)b * NM + m) * ND;
        float v0 = mrow[lane] * sOmE[lane] + sAdd[lane];
        float v1 = mrow[lane + 64] * sOmE[lane + 64] + sAdd[lane + 64];
        float v2 = 0.f;
        const bool has2 = lane < 32;
        if (has2) v2 = mrow[lane + 128] * sOmE[lane + 128] + sAdd[lane + 128];
        float s  = v0 + v1 + v2;
        float sq = v0 * v0 + v1 * v1 + v2 * v2;
#pragma unroll
        for (int off = 32; off; off >>= 1) {
            s  += __shfl_xor(s, off);
            sq += __shfl_xor(sq, off);
        }
        float mu   = s * (1.0f / ND);
        float var  = sq * (1.0f / ND) - mu * mu;
        float rstd = rsqrtf(var + 1e-5f);
        float* orow = new_mem + ((size_t)b * NM + m) * ND;
        orow[lane]      = (v0 - mu) * rstd;
        orow[lane + 64] = (v1 - mu) * rstd;
        if (has2) orow[lane + 128] = (v2 - mu) * rstd;
    }
}

extern "C" void kernel_launch(void* const* d_in, const int* in_sizes, int n_in,
                              void* d_out, int out_size, void* d_ws, size_t ws_size,
                              hipStream_t stream) {
    const float* query  = (const float*)d_in[0];
    const float* iface  = (const float*)d_in[1];
    const float* memory = (const float*)d_in[2];
    const float* Wrk    = (const float*)d_in[3];
    const float* Wrv    = (const float*)d_in[4];
    const float* Wwk    = (const float*)d_in[5];
    const float* Wwe    = (const float*)d_in[6];
    const float* Wwa    = (const float*)d_in[7];

    float* read_out = (float*)d_out;                       // [32][4096][160]
    float* new_mem  = (float*)d_out + (size_t)NB * NS * ND; // [32][16][160]
    float* ipart    = (float*)d_ws;                        // 32*64*160 f32 = 1.31 MB

    dim3 grid1(NCHUNK, NB);
    ulm_read_kernel<<<grid1, 256, 0, stream>>>(query, iface, memory, Wrk, Wrv,
                                               read_out, ipart);
    ulm_write_kernel<<<NB, 256, 0, stream>>>(memory, Wwk, Wwe, Wwa, ipart, new_mem);
}

// Round 2
// 63.604 us; speedup vs baseline: 1.6095x; 1.6095x over previous
//
#include <hip/hip_runtime.h>
#include <math.h>

#define NB 32
#define NS 4096
#define ND 160
#define ND4 40              // ND in float4
#define NM 16
#define NR 16
#define TPB 128             // tokens per block
#define NCB (NS / TPB)      // 32 chunks per batch

// ---------------------------------------------------------------------------
// Kernel 1: read path via per-batch folded matrices
//   K[m][d] = 0.25 * sum_r mem16[m][r] * Wrk[r][d]
//   V[m][d] =        sum_r mem16[m][r] * Wrv[d][r]
//   scores[s][m] = dot(query[s], K[m]);  out[s] = softmax(scores)·V
// Fused: partial column-sums of `interface` -> ipart.
// grid = (NCB, NB), block = 256.  4 lanes/token, 2 tokens/group.
// ---------------------------------------------------------------------------
__global__ __launch_bounds__(256) void ulm_read_kernel(
    const float* __restrict__ query,
    const float* __restrict__ iface,
    const float* __restrict__ memory,
    const float* __restrict__ Wrk,     // [NR][ND]
    const float* __restrict__ Wrv,     // [ND][NR]
    float* __restrict__ read_out,      // [NB][NS][ND]
    float* __restrict__ ipart)         // [NB][NCB][ND]
{
    __shared__ __align__(16) float sK[NM * ND];   // 10 KB
    __shared__ __align__(16) float sV[NM * ND];   // 10 KB
    __shared__ float sM16[NM * NR];               // 1 KB
    __shared__ float4 sIred[4 * ND4];             // 2.5 KB

    const int t = threadIdx.x;
    const int chunk = blockIdx.x;
    const int b = blockIdx.y;
    const int s0 = chunk * TPB;

    // --- stage memory[b][:][:16] ------------------------------------------
    {
        int m = t >> 4, r = t & 15;
        sM16[t] = memory[((size_t)b * NM + m) * ND + r];
    }
    __syncthreads();

    // --- fold weights: K,V (16x160 each) into LDS, one thread per d --------
    if (t < ND) {
        float wk[NR], wv[NR];
#pragma unroll
        for (int r = 0; r < NR; ++r) wk[r] = Wrk[r * ND + t];
        const float4* wrv4 = reinterpret_cast<const float4*>(Wrv + t * NR);
#pragma unroll
        for (int j = 0; j < 4; ++j) {
            float4 v = wrv4[j];
            wv[j * 4 + 0] = v.x; wv[j * 4 + 1] = v.y;
            wv[j * 4 + 2] = v.z; wv[j * 4 + 3] = v.w;
        }
#pragma unroll
        for (int m = 0; m < NM; ++m) {
            float aK = 0.f, aV = 0.f;
#pragma unroll
            for (int r = 0; r < NR; ++r) {
                float mv = sM16[m * NR + r];
                aK += mv * wk[r];
                aV += mv * wv[r];
            }
            sK[m * ND + t] = aK * 0.25f;   // fold 1/sqrt(R)
            sV[m * ND + t] = aV;
        }
    }
    __syncthreads();

    const float4* sK4 = reinterpret_cast<const float4*>(sK);
    const float4* sV4 = reinterpret_cast<const float4*>(sV);

    const int l = t & 3;                  // lane in 4-lane group
    const int G = t >> 2;                 // 0..63 group id in block
    const int tok0 = G * 2, tok1 = tok0 + 1;

    const float4* q4 = reinterpret_cast<const float4*>(query + ((size_t)b * NS + s0) * ND);

    // --- scores: 16 dots of length 160, distributed over 4 lanes ----------
    float sc0[NM], sc1[NM];
#pragma unroll
    for (int m = 0; m < NM; ++m) { sc0[m] = 0.f; sc1[m] = 0.f; }

#pragma unroll
    for (int k = 0; k < 10; ++k) {
        float4 qa = q4[tok0 * ND4 + l + 4 * k];
        float4 qb = q4[tok1 * ND4 + l + 4 * k];
#pragma unroll
        for (int m = 0; m < NM; ++m) {
            float4 kv = sK4[m * ND4 + l + 4 * k];
            sc0[m] += qa.x * kv.x + qa.y * kv.y + qa.z * kv.z + qa.w * kv.w;
            sc1[m] += qb.x * kv.x + qb.y * kv.y + qb.z * kv.z + qb.w * kv.w;
        }
    }
#pragma unroll
    for (int m = 0; m < NM; ++m) {
        sc0[m] += __shfl_xor(sc0[m], 1); sc0[m] += __shfl_xor(sc0[m], 2);
        sc1[m] += __shfl_xor(sc1[m], 1); sc1[m] += __shfl_xor(sc1[m], 2);
    }

    // --- softmax (redundant per lane; 16-wide) -----------------------------
    float mx0 = -1e30f, mx1 = -1e30f;
#pragma unroll
    for (int m = 0; m < NM; ++m) { mx0 = fmaxf(mx0, sc0[m]); mx1 = fmaxf(mx1, sc1[m]); }
    float sm0 = 0.f, sm1 = 0.f;
#pragma unroll
    for (int m = 0; m < NM; ++m) {
        sc0[m] = __expf(sc0[m] - mx0); sm0 += sc0[m];
        sc1[m] = __expf(sc1[m] - mx1); sm1 += sc1[m];
    }
    float inv0 = 1.f / sm0, inv1 = 1.f / sm1;
#pragma unroll
    for (int m = 0; m < NM; ++m) { sc0[m] *= inv0; sc1[m] *= inv1; }

    // --- out = attn · V -----------------------------------------------------
    float4* out4 = reinterpret_cast<float4*>(read_out + ((size_t)b * NS + s0) * ND);
#pragma unroll
    for (int k = 0; k < 10; ++k) {
        float4 o0 = make_float4(0.f, 0.f, 0.f, 0.f);
        float4 o1 = make_float4(0.f, 0.f, 0.f, 0.f);
#pragma unroll
        for (int m = 0; m < NM; ++m) {
            float4 vv = sV4[m * ND4 + l + 4 * k];
            o0.x += sc0[m] * vv.x; o0.y += sc0[m] * vv.y;
            o0.z += sc0[m] * vv.z; o0.w += sc0[m] * vv.w;
            o1.x += sc1[m] * vv.x; o1.y += sc1[m] * vv.y;
            o1.z += sc1[m] * vv.z; o1.w += sc1[m] * vv.w;
        }
        out4[tok0 * ND4 + l + 4 * k] = o0;
        out4[tok1 * ND4 + l + 4 * k] = o1;
    }

    // --- fused interface partial column-sums -------------------------------
    const float4* i4 = reinterpret_cast<const float4*>(iface + ((size_t)b * NS + s0) * ND);
    const int w = t >> 6;
#pragma unroll
    for (int k = 0; k < 10; ++k) {
        float4 va = i4[tok0 * ND4 + l + 4 * k];
        float4 vb = i4[tok1 * ND4 + l + 4 * k];
        float x = va.x + vb.x, y = va.y + vb.y;
        float z = va.z + vb.z, u = va.w + vb.w;
#pragma unroll
        for (int off = 4; off <= 32; off <<= 1) {
            x += __shfl_xor(x, off); y += __shfl_xor(y, off);
            z += __shfl_xor(z, off); u += __shfl_xor(u, off);
        }
        if ((t & 63) < 4) sIred[w * ND4 + k * 4 + l] = make_float4(x, y, z, u);
    }
    __syncthreads();
    if (t < ND4) {
        float4 a0 = sIred[t], a1 = sIred[ND4 + t];
        float4 a2 = sIred[2 * ND4 + t], a3 = sIred[3 * ND4 + t];
        float4 tot = make_float4(a0.x + a1.x + a2.x + a3.x,
                                 a0.y + a1.y + a2.y + a3.y,
                                 a0.z + a1.z + a2.z + a3.z,
                                 a0.w + a1.w + a2.w + a3.w);
        reinterpret_cast<float4*>(ipart + ((size_t)(b * NCB + chunk)) * ND)[t] = tot;
    }
}

// ---------------------------------------------------------------------------
// Kernel 2: write path. i_mean -> i_proj -> erase/add -> layer_norm(new_mem)
// grid = NB, block = 256
// ---------------------------------------------------------------------------
__global__ __launch_bounds__(256) void ulm_write_kernel(
    const float* __restrict__ memory,
    const float* __restrict__ Wwk,     // [NR][ND]
    const float* __restrict__ Wwe,     // [ND][NR]
    const float* __restrict__ Wwa,     // [ND][NR]
    const float* __restrict__ ipart,   // [NB][NCB][ND]
    float* __restrict__ new_mem)       // [NB][NM][ND]
{
    __shared__ float sIm[ND];
    __shared__ float sIp[NR];
    __shared__ float sOmE[ND];   // 1 - erase
    __shared__ float sAdd[ND];

    const int b = blockIdx.x;
    const int t = threadIdx.x;

    if (t < ND) {
        float acc = 0.f;
        for (int c = 0; c < NCB; ++c)
            acc += ipart[((size_t)(b * NCB + c)) * ND + t];
        sIm[t] = acc * (1.0f / NS);
    }
    __syncthreads();

    if (t < NR) {
        float acc = 0.f;
        for (int d = 0; d < ND; ++d) acc += sIm[d] * Wwk[t * ND + d];
        sIp[t] = acc;
    }
    __syncthreads();

    if (t < ND) {
        float e = 0.f, a = 0.f;
#pragma unroll
        for (int r = 0; r < NR; ++r) {
            float ip = sIp[r];
            e += ip * Wwe[t * NR + r];
            a += ip * Wwa[t * NR + r];
        }
        sOmE[t] = 1.0f - 1.0f / (1.0f + __expf(-e));
        sAdd[t] = a;
    }
    __syncthreads();

    // layer norm each of the 16 memory rows; one wave per row
    const int wave = t >> 6, lane = t & 63;
    for (int m = wave; m < NM; m += 4) {
        const float* mrow = memory + ((size_t)b * NM + m) * ND;
        float v0 = mrow[lane] * sOmE[lane] + sAdd[lane];
        float v1 = mrow[lane + 64] * sOmE[lane + 64] + sAdd[lane + 64];
        float v2 = 0.f;
        const bool has2 = lane < 32;
        if (has2) v2 = mrow[lane + 128] * sOmE[lane + 128] + sAdd[lane + 128];
        float s  = v0 + v1 + v2;
        float sq = v0 * v0 + v1 * v1 + v2 * v2;
#pragma unroll
        for (int off = 32; off; off >>= 1) {
            s  += __shfl_xor(s, off);
            sq += __shfl_xor(sq, off);
        }
        float mu   = s * (1.0f / ND);
        float var  = sq * (1.0f / ND) - mu * mu;
        float rstd = rsqrtf(var + 1e-5f);
        float* orow = new_mem + ((size_t)b * NM + m) * ND;
        orow[lane]      = (v0 - mu) * rstd;
        orow[lane + 64] = (v1 - mu) * rstd;
        if (has2) orow[lane + 128] = (v2 - mu) * rstd;
    }
}

extern "C" void kernel_launch(void* const* d_in, const int* in_sizes, int n_in,
                              void* d_out, int out_size, void* d_ws, size_t ws_size,
                              hipStream_t stream) {
    const float* query  = (const float*)d_in[0];
    const float* iface  = (const float*)d_in[1];
    const float* memory = (const float*)d_in[2];
    const float* Wrk    = (const float*)d_in[3];
    const float* Wrv    = (const float*)d_in[4];
    const float* Wwk    = (const float*)d_in[5];
    const float* Wwe    = (const float*)d_in[6];
    const float* Wwa    = (const float*)d_in[7];

    float* read_out = (float*)d_out;                        // [32][4096][160]
    float* new_mem  = (float*)d_out + (size_t)NB * NS * ND; // [32][16][160]
    float* ipart    = (float*)d_ws;                         // 32*32*160 f32

    dim3 grid1(NCB, NB);
    ulm_read_kernel<<<grid1, 256, 0, stream>>>(query, iface, memory, Wrk, Wrv,
                                               read_out, ipart);
    ulm_write_kernel<<<NB, 256, 0, stream>>>(memory, Wwk, Wwe, Wwa, ipart, new_mem);
}

// Round 3
// 62.709 us; speedup vs baseline: 1.6325x; 1.0143x over previous
//
#include <hip/hip_runtime.h>
#include <math.h>

#define NB 32
#define NS 4096
#define ND 160
#define ND4 40              // ND in float4
#define NM 16
#define NR 16
#define TPB 64              // tokens per block
#define NCB (NS / TPB)      // 64 chunks per batch

// ---------------------------------------------------------------------------
// Kernel 1: read path via per-batch folded matrices
//   K[m][d] = 0.25 * sum_r mem16[m][r] * Wrk[r][d]
//   V[m][d] =        sum_r mem16[m][r] * Wrv[d][r]
//   scores[s][m] = dot(query[s], K[m]);  out[s] = softmax(scores)·V
// Fused: partial column-sums of `interface` -> ipart.
// grid = (NCB, NB), block = 256.  8 lanes per 2-token group.
// ---------------------------------------------------------------------------
__global__ __launch_bounds__(256, 5) void ulm_read_kernel(
    const float* __restrict__ query,
    const float* __restrict__ iface,
    const float* __restrict__ memory,
    const float* __restrict__ Wrk,     // [NR][ND]
    const float* __restrict__ Wrv,     // [ND][NR]
    float* __restrict__ read_out,      // [NB][NS][ND]
    float* __restrict__ ipart)         // [NB][NCB][ND]
{
    __shared__ __align__(16) float sK[NM * ND];   // 10 KB
    __shared__ __align__(16) float sV[NM * ND];   // 10 KB
    __shared__ float sM16[NM * NR];               // 1 KB
    __shared__ float4 sIred[4 * ND4];             // 2.5 KB

    const int t = threadIdx.x;
    const int chunk = blockIdx.x;
    const int b = blockIdx.y;
    const int s0 = chunk * TPB;

    // --- stage memory[b][:][:16] (256 threads = 256 elements) --------------
    {
        int m = t >> 4, r = t & 15;
        sM16[t] = memory[((size_t)b * NM + m) * ND + r];
    }
    __syncthreads();

    // --- fold weights: K,V (16x160 each) into LDS, one thread per d --------
    if (t < ND) {
        float wk[NR], wv[NR];
#pragma unroll
        for (int r = 0; r < NR; ++r) wk[r] = Wrk[r * ND + t];
        const float4* wrv4 = reinterpret_cast<const float4*>(Wrv + t * NR);
#pragma unroll
        for (int j = 0; j < 4; ++j) {
            float4 v = wrv4[j];
            wv[j * 4 + 0] = v.x; wv[j * 4 + 1] = v.y;
            wv[j * 4 + 2] = v.z; wv[j * 4 + 3] = v.w;
        }
#pragma unroll
        for (int m = 0; m < NM; ++m) {
            float aK = 0.f, aV = 0.f;
#pragma unroll
            for (int r = 0; r < NR; ++r) {
                float mv = sM16[m * NR + r];
                aK += mv * wk[r];
                aV += mv * wv[r];
            }
            sK[m * ND + t] = aK * 0.25f;   // fold 1/sqrt(R)
            sV[m * ND + t] = aV;
        }
    }
    __syncthreads();

    const float4* sK4 = reinterpret_cast<const float4*>(sK);
    const float4* sV4 = reinterpret_cast<const float4*>(sV);

    const int l = t & 7;                  // lane in 8-lane group
    const int G = t >> 3;                 // 0..31 group id in block
    const int tok0 = G * 2, tok1 = tok0 + 1;

    const float4* q4 = reinterpret_cast<const float4*>(query + ((size_t)b * NS + s0) * ND);

    // --- scores: 16 dots of length 160, distributed over 8 lanes ----------
    float sc0[NM], sc1[NM];
#pragma unroll
    for (int m = 0; m < NM; ++m) { sc0[m] = 0.f; sc1[m] = 0.f; }

#pragma unroll
    for (int k = 0; k < 5; ++k) {
        float4 qa = q4[tok0 * ND4 + l + 8 * k];
        float4 qb = q4[tok1 * ND4 + l + 8 * k];
#pragma unroll
        for (int m = 0; m < NM; ++m) {
            float4 kv = sK4[m * ND4 + l + 8 * k];
            sc0[m] += qa.x * kv.x + qa.y * kv.y + qa.z * kv.z + qa.w * kv.w;
            sc1[m] += qb.x * kv.x + qb.y * kv.y + qb.z * kv.z + qb.w * kv.w;
        }
    }
#pragma unroll
    for (int m = 0; m < NM; ++m) {
        sc0[m] += __shfl_xor(sc0[m], 1);
        sc0[m] += __shfl_xor(sc0[m], 2);
        sc0[m] += __shfl_xor(sc0[m], 4);
        sc1[m] += __shfl_xor(sc1[m], 1);
        sc1[m] += __shfl_xor(sc1[m], 2);
        sc1[m] += __shfl_xor(sc1[m], 4);
    }

    // --- softmax (redundant per lane; 16-wide) -----------------------------
    float mx0 = -1e30f, mx1 = -1e30f;
#pragma unroll
    for (int m = 0; m < NM; ++m) { mx0 = fmaxf(mx0, sc0[m]); mx1 = fmaxf(mx1, sc1[m]); }
    float sm0 = 0.f, sm1 = 0.f;
#pragma unroll
    for (int m = 0; m < NM; ++m) {
        sc0[m] = __expf(sc0[m] - mx0); sm0 += sc0[m];
        sc1[m] = __expf(sc1[m] - mx1); sm1 += sc1[m];
    }
    float inv0 = 1.f / sm0, inv1 = 1.f / sm1;
#pragma unroll
    for (int m = 0; m < NM; ++m) { sc0[m] *= inv0; sc1[m] *= inv1; }

    // --- interface partial column-sums (loads issued here; PV below hides
    //     their latency). Positions: (l + 8k); reduce across 8 groups/wave. --
    const float4* i4 = reinterpret_cast<const float4*>(iface + ((size_t)b * NS + s0) * ND);
    const int w = t >> 6;
#pragma unroll
    for (int k = 0; k < 5; ++k) {
        float4 va = i4[tok0 * ND4 + l + 8 * k];
        float4 vb = i4[tok1 * ND4 + l + 8 * k];
        float x = va.x + vb.x, y = va.y + vb.y;
        float z = va.z + vb.z, u = va.w + vb.w;
#pragma unroll
        for (int off = 8; off <= 32; off <<= 1) {
            x += __shfl_xor(x, off); y += __shfl_xor(y, off);
            z += __shfl_xor(z, off); u += __shfl_xor(u, off);
        }
        if ((t & 63) < 8) sIred[w * ND4 + k * 8 + l] = make_float4(x, y, z, u);
    }

    // --- out = attn · V -----------------------------------------------------
    float4* out4 = reinterpret_cast<float4*>(read_out + ((size_t)b * NS + s0) * ND);
#pragma unroll
    for (int k = 0; k < 5; ++k) {
        float4 o0 = make_float4(0.f, 0.f, 0.f, 0.f);
        float4 o1 = make_float4(0.f, 0.f, 0.f, 0.f);
#pragma unroll
        for (int m = 0; m < NM; ++m) {
            float4 vv = sV4[m * ND4 + l + 8 * k];
            o0.x += sc0[m] * vv.x; o0.y += sc0[m] * vv.y;
            o0.z += sc0[m] * vv.z; o0.w += sc0[m] * vv.w;
            o1.x += sc1[m] * vv.x; o1.y += sc1[m] * vv.y;
            o1.z += sc1[m] * vv.z; o1.w += sc1[m] * vv.w;
        }
        out4[tok0 * ND4 + l + 8 * k] = o0;
        out4[tok1 * ND4 + l + 8 * k] = o1;
    }

    // --- finish interface reduction: 4 wave-partials -> 1, store to ws -----
    __syncthreads();
    if (t < ND4) {
        float4 a0 = sIred[t], a1 = sIred[ND4 + t];
        float4 a2 = sIred[2 * ND4 + t], a3 = sIred[3 * ND4 + t];
        float4 tot = make_float4(a0.x + a1.x + a2.x + a3.x,
                                 a0.y + a1.y + a2.y + a3.y,
                                 a0.z + a1.z + a2.z + a3.z,
                                 a0.w + a1.w + a2.w + a3.w);
        reinterpret_cast<float4*>(ipart + ((size_t)(b * NCB + chunk)) * ND)[t] = tot;
    }
}

// ---------------------------------------------------------------------------
// Kernel 2: write path. i_mean -> i_proj -> erase/add -> layer_norm(new_mem)
// grid = NB, block = 256
// ---------------------------------------------------------------------------
__global__ __launch_bounds__(256) void ulm_write_kernel(
    const float* __restrict__ memory,
    const float* __restrict__ Wwk,     // [NR][ND]
    const float* __restrict__ Wwe,     // [ND][NR]
    const float* __restrict__ Wwa,     // [ND][NR]
    const float* __restrict__ ipart,   // [NB][NCB][ND]
    float* __restrict__ new_mem)       // [NB][NM][ND]
{
    __shared__ float sIm[ND];
    __shared__ float sIp[NR];
    __shared__ float sOmE[ND];   // 1 - erase
    __shared__ float sAdd[ND];

    const int b = blockIdx.x;
    const int t = threadIdx.x;

    if (t < ND) {
        float acc = 0.f;
        for (int c = 0; c < NCB; ++c)
            acc += ipart[((size_t)(b * NCB + c)) * ND + t];
        sIm[t] = acc * (1.0f / NS);
    }
    __syncthreads();

    if (t < NR) {
        float acc = 0.f;
        for (int d = 0; d < ND; ++d) acc += sIm[d] * Wwk[t * ND + d];
        sIp[t] = acc;
    }
    __syncthreads();

    if (t < ND) {
        float e = 0.f, a = 0.f;
#pragma unroll
        for (int r = 0; r < NR; ++r) {
            float ip = sIp[r];
            e += ip * Wwe[t * NR + r];
            a += ip * Wwa[t * NR + r];
        }
        sOmE[t] = 1.0f - 1.0f / (1.0f + __expf(-e));
        sAdd[t] = a;
    }
    __syncthreads();

    // layer norm each of the 16 memory rows; one wave per row
    const int wave = t >> 6, lane = t & 63;
    for (int m = wave; m < NM; m += 4) {
        const float* mrow = memory + ((size_t)b * NM + m) * ND;
        float v0 = mrow[lane] * sOmE[lane] + sAdd[lane];
        float v1 = mrow[lane + 64] * sOmE[lane + 64] + sAdd[lane + 64];
        float v2 = 0.f;
        const bool has2 = lane < 32;
        if (has2) v2 = mrow[lane + 128] * sOmE[lane + 128] + sAdd[lane + 128];
        float s  = v0 + v1 + v2;
        float sq = v0 * v0 + v1 * v1 + v2 * v2;
#pragma unroll
        for (int off = 32; off; off >>= 1) {
            s  += __shfl_xor(s, off);
            sq += __shfl_xor(sq, off);
        }
        float mu   = s * (1.0f / ND);
        float var  = sq * (1.0f / ND) - mu * mu;
        float rstd = rsqrtf(var + 1e-5f);
        float* orow = new_mem + ((size_t)b * NM + m) * ND;
        orow[lane]      = (v0 - mu) * rstd;
        orow[lane + 64] = (v1 - mu) * rstd;
        if (has2) orow[lane + 128] = (v2 - mu) * rstd;
    }
}

extern "C" void kernel_launch(void* const* d_in, const int* in_sizes, int n_in,
                              void* d_out, int out_size, void* d_ws, size_t ws_size,
                              hipStream_t stream) {
    const float* query  = (const float*)d_in[0];
    const float* iface  = (const float*)d_in[1];
    const float* memory = (const float*)d_in[2];
    const float* Wrk    = (const float*)d_in[3];
    const float* Wrv    = (const float*)d_in[4];
    const float* Wwk    = (const float*)d_in[5];
    const float* Wwe    = (const float*)d_in[6];
    const float* Wwa    = (const float*)d_in[7];

    float* read_out = (float*)d_out;                        // [32][4096][160]
    float* new_mem  = (float*)d_out + (size_t)NB * NS * ND; // [32][16][160]
    float* ipart    = (float*)d_ws;                         // 32*64*160 f32 = 1.31 MB

    dim3 grid1(NCB, NB);
    ulm_read_kernel<<<grid1, 256, 0, stream>>>(query, iface, memory, Wrk, Wrv,
                                               read_out, ipart);
    ulm_write_kernel<<<NB, 256, 0, stream>>>(memory, Wwk, Wwe, Wwa, ipart, new_mem);
}